// Round 3
// baseline (1271.596 us; speedup 1.0000x reference)
//
#include <hip/hip_runtime.h>

#define B_   2
#define S_   1024
#define D_   1024
#define H_   16
#define HD_  64
#define L_   4
#define MFF  2730
#define MPAD 2816
#define V_   32000

typedef __attribute__((ext_vector_type(8))) short   short8;
typedef __attribute__((ext_vector_type(4))) float   floatx4;

__device__ __forceinline__ unsigned short f2b(float f) {
  unsigned u = __float_as_uint(f);
  u += 0x7fffu + ((u >> 16) & 1u);
  return (unsigned short)(u >> 16);
}
__device__ __forceinline__ float b2f(unsigned short s) {
  return __uint_as_float(((unsigned)s) << 16);
}

// async global->LDS, 16B per lane. LDS dst must be wave-uniform base; HW adds lane*16.
__device__ __forceinline__ void gload16(const unsigned short* g, unsigned short* l) {
  __builtin_amdgcn_global_load_lds(
      (const __attribute__((address_space(1))) unsigned int*)(unsigned long long)g,
      (__attribute__((address_space(3))) unsigned int*)(unsigned int)(unsigned long long)l,
      16, 0, 0);
}

// raw workgroup barrier with compiler memory fences (no vmcnt drain).
__device__ __forceinline__ void wgbar() {
  asm volatile("" ::: "memory");
  __builtin_amdgcn_s_barrier();
  asm volatile("" ::: "memory");
}

// ---------------- embed gather ----------------
__global__ __launch_bounds__(256) void embed_kernel(const int* __restrict__ tokens,
                                                    const float* __restrict__ embed,
                                                    float* __restrict__ x) {
  int row = blockIdx.x;
  int tok = tokens[row];
  int c = threadIdx.x * 4;
  float4 v = *(const float4*)&embed[(size_t)tok * D_ + c];
  *(float4*)&x[(size_t)row * D_ + c] = v;
}

// ---------------- rmsnorm (f32 in -> bf16 out) ----------------
__global__ __launch_bounds__(256) void rmsnorm_bf(const float* __restrict__ x,
                                                  const float* __restrict__ w,
                                                  unsigned short* __restrict__ out) {
  int row = blockIdx.x, t = threadIdx.x;
  float4 xv = *(const float4*)&x[(size_t)row * D_ + t * 4];
  float ss = xv.x * xv.x + xv.y * xv.y + xv.z * xv.z + xv.w * xv.w;
  #pragma unroll
  for (int off = 1; off < 64; off <<= 1) ss += __shfl_xor(ss, off, 64);
  __shared__ float sred[4];
  if ((t & 63) == 0) sred[t >> 6] = ss;
  __syncthreads();
  ss = sred[0] + sred[1] + sred[2] + sred[3];
  float rr = rsqrtf(ss * (1.f / (float)D_) + 1e-6f);
  float4 wv = *(const float4*)&w[t * 4];
  size_t o = (size_t)row * D_ + t * 4;
  out[o + 0] = f2b(xv.x * rr * wv.x);
  out[o + 1] = f2b(xv.y * rr * wv.y);
  out[o + 2] = f2b(xv.z * rr * wv.z);
  out[o + 3] = f2b(xv.w * rr * wv.w);
}

// ---------------- final rmsnorm (last token rows, f32 out) ----------------
__global__ __launch_bounds__(256) void rmsnorm_final(const float* __restrict__ x,
                                                     const float* __restrict__ w,
                                                     float* __restrict__ out) {
  int b = blockIdx.x, t = threadIdx.x;
  const float* xr = x + ((size_t)b * S_ + (S_ - 1)) * D_;
  float4 xv = *(const float4*)&xr[t * 4];
  float ss = xv.x * xv.x + xv.y * xv.y + xv.z * xv.z + xv.w * xv.w;
  #pragma unroll
  for (int off = 1; off < 64; off <<= 1) ss += __shfl_xor(ss, off, 64);
  __shared__ float sred[4];
  if ((t & 63) == 0) sred[t >> 6] = ss;
  __syncthreads();
  ss = sred[0] + sred[1] + sred[2] + sred[3];
  float rr = rsqrtf(ss * (1.f / (float)D_) + 1e-6f);
  float4 wv = *(const float4*)&w[t * 4];
  size_t o = (size_t)b * D_ + t * 4;
  out[o + 0] = xv.x * rr * wv.x;
  out[o + 1] = xv.y * rr * wv.y;
  out[o + 2] = xv.z * rr * wv.z;
  out[o + 3] = xv.w * rr * wv.w;
}

// -------- weight transpose + f32->bf16, 64x64 tiles (K x N -> Npad x Kpad) --------
__global__ __launch_bounds__(256) void transpose_conv(const float* __restrict__ W,
                                                      unsigned short* __restrict__ Wt,
                                                      int K, int N, int Kpad, int Npad) {
  __shared__ float tile[64][65];
  const int tx = threadIdx.x & 15, ty = threadIdx.x >> 4;
  const int k0 = blockIdx.y * 64, n0 = blockIdx.x * 64;
  #pragma unroll
  for (int i = 0; i < 4; i++) {
    int kk = k0 + ty + i * 16;
    int nn = n0 + tx * 4;
    float4 v = {0.f, 0.f, 0.f, 0.f};
    if (kk < K) {
      if (nn + 3 < N) v = *(const float4*)&W[(size_t)kk * N + nn];
      else {
        if (nn + 0 < N) v.x = W[(size_t)kk * N + nn + 0];
        if (nn + 1 < N) v.y = W[(size_t)kk * N + nn + 1];
        if (nn + 2 < N) v.z = W[(size_t)kk * N + nn + 2];
      }
    }
    tile[ty + i * 16][tx * 4 + 0] = v.x;
    tile[ty + i * 16][tx * 4 + 1] = v.y;
    tile[ty + i * 16][tx * 4 + 2] = v.z;
    tile[ty + i * 16][tx * 4 + 3] = v.w;
  }
  __syncthreads();
  #pragma unroll
  for (int i = 0; i < 4; i++) {
    int nn = n0 + ty + i * 16;
    int kk = k0 + tx * 4;
    if (nn < Npad && kk < Kpad) {
      ushort4 o;
      o.x = f2b(tile[tx * 4 + 0][ty + i * 16]);
      o.y = f2b(tile[tx * 4 + 1][ty + i * 16]);
      o.z = f2b(tile[tx * 4 + 2][ty + i * 16]);
      o.w = f2b(tile[tx * 4 + 3][ty + i * 16]);
      *(ushort4*)&Wt[(size_t)nn * Kpad + kk] = o;
    }
  }
}

// ---- bf16 MFMA GEMM, A[M][K], B^T[N][K], MTILE x 128 tile ----
// 2-deep double-buffered pipeline, counted vmcnt (T3 minimum-2-phase + T4).
// XCD-aware swizzle (T1): flat%8 = XCD (round-robin dispatch). Each XCD gets
// a contiguous column-major chunk: its few B n-panels stay hot in its 4MiB L2
// while A streams (also mostly L2-resident). Baseline traffic was
// nblocks*512KB (e.g. qkv 192MB vs 10MB compulsory) -> traffic-bound.
// All grids have nwg%8==0 so the remap is bijective.
// EPI: 0 = f32 out, 1 = f32 out + residual, 2 = bf16 out
template <int EPI, int MTILE>
__global__ __launch_bounds__(256) void gemm_bt(const unsigned short* __restrict__ A,
                                               const unsigned short* __restrict__ B,
                                               const float* __restrict__ bias,
                                               const float* __restrict__ res,
                                               void* __restrict__ Cout,
                                               int N, int K, int lda, int ldb, int ldc,
                                               int Nlog) {
  constexpr int MW = MTILE / 32;           // m-frags per wave
  constexpr int LOADS = MTILE / 64 + 2;    // gload16 per wave per stage
  __shared__ unsigned short As[2][MTILE * 32];
  __shared__ unsigned short Bs[2][128 * 32];
  const int tid = threadIdx.x;
  const int lane = tid & 63, wave = tid >> 6;
  // XCD swizzle: chunk-contiguous, m fastest within chunk (n-panels hot).
  const int MBc = gridDim.y, NBc = gridDim.x;
  const int nwg = MBc * NBc;
  const int flat = blockIdx.y * NBc + blockIdx.x;
  const int swz = (flat & 7) * (nwg >> 3) + (flat >> 3);
  const int m0 = (swz % MBc) * MTILE, n0 = (swz / MBc) * 128;
  const int rS = tid >> 2;
  const int kS = (tid & 3) * 8;
  const int fr = lane & 15;
  const int kq = (lane >> 4) * 8;
  const int wm = (wave & 1) * (MTILE / 2), wn = (wave >> 1) * 64;

  const unsigned short* Ab = A + (size_t)(m0 + rS) * lda + kS;
  const unsigned short* Bb = B + (size_t)(n0 + rS) * ldb + kS;

  floatx4 zv = {0.f, 0.f, 0.f, 0.f};
  floatx4 acc[MW][4];
  #pragma unroll
  for (int mi = 0; mi < MW; mi++)
    #pragma unroll
    for (int ni = 0; ni < 4; ni++) acc[mi][ni] = zv;

  auto stage = [&](int buf, int k0) {
    #pragma unroll
    for (int i = 0; i < MTILE / 64; i++)
      gload16(Ab + (size_t)(i * 64) * lda + k0, &As[buf][i * 2048 + wave * 512]);
    #pragma unroll
    for (int i = 0; i < 2; i++)
      gload16(Bb + (size_t)(i * 64) * ldb + k0, &Bs[buf][i * 2048 + wave * 512]);
  };

  const int nk = K / 32;
  stage(0, 0);
  int cur = 0;
  for (int kt = 0; kt < nk; kt++) {
    if (kt + 1 < nk) {
      stage(cur ^ 1, (kt + 1) * 32);
      if constexpr (LOADS == 4)
        asm volatile("s_waitcnt vmcnt(4)" ::: "memory");
      else
        asm volatile("s_waitcnt vmcnt(3)" ::: "memory");
    } else {
      asm volatile("s_waitcnt vmcnt(0)" ::: "memory");
    }
    wgbar();  // current tile fully in LDS (each wave waited its own loads)
    short8 af[MW], bfv[4];
    #pragma unroll
    for (int mi = 0; mi < MW; mi++) af[mi] = *(const short8*)&As[cur][(wm + mi * 16 + fr) * 32 + kq];
    #pragma unroll
    for (int ni = 0; ni < 4; ni++) bfv[ni] = *(const short8*)&Bs[cur][(wn + ni * 16 + fr) * 32 + kq];
    #pragma unroll
    for (int mi = 0; mi < MW; mi++)
      #pragma unroll
      for (int ni = 0; ni < 4; ni++)
        acc[mi][ni] = __builtin_amdgcn_mfma_f32_16x16x32_bf16(af[mi], bfv[ni], acc[mi][ni], 0, 0, 0);
    wgbar();  // all waves done reading buf[cur]; safe to stage into it next iter
    cur ^= 1;
  }

  const int cr = (lane >> 4) * 4;
  const int cc = lane & 15;
  #pragma unroll
  for (int mi = 0; mi < MW; mi++) {
    #pragma unroll
    for (int ni = 0; ni < 4; ni++) {
      int col = n0 + wn + ni * 16 + cc;
      float bv = (col < Nlog) ? bias[col] : 0.f;
      #pragma unroll
      for (int r = 0; r < 4; r++) {
        int row = m0 + wm + mi * 16 + cr + r;
        float val = acc[mi][ni][r] + bv;
        if constexpr (EPI == 1) val += res[(size_t)row * ldc + col];
        if constexpr (EPI == 2)
          ((unsigned short*)Cout)[(size_t)row * ldc + col] = f2b(val);
        else
          ((float*)Cout)[(size_t)row * ldc + col] = val;
      }
    }
  }
}

// ---------------- rope table (double precision) ----------------
__global__ __launch_bounds__(256) void rope_table(float* __restrict__ cs, float* __restrict__ sn) {
  int i = blockIdx.x * 256 + threadIdx.x;
  int s = i >> 5, f = i & 31;
  double inv = pow(10000.0, -(double)(2 * f) / 64.0);
  double ang = (double)s * inv;
  cs[i] = (float)cos(ang);
  sn[i] = (float)sin(ang);
}

// ------- rope apply (qkv bf16 -> q,k,v bf16 in (B*H,S,HD)) -------
__global__ __launch_bounds__(256) void rope_apply(const unsigned short* __restrict__ qkv,
                                                  const float* __restrict__ cs,
                                                  const float* __restrict__ sn,
                                                  unsigned short* __restrict__ q,
                                                  unsigned short* __restrict__ k,
                                                  unsigned short* __restrict__ v) {
  int i = blockIdx.x * 256 + threadIdx.x;  // B*S*H*32
  int pr = i & 31;
  int h  = (i >> 5) & 15;
  int s  = (i >> 9) & 1023;
  int b  = i >> 19;
  size_t base = ((size_t)(b * S_ + s)) * (3 * D_) + h * HD_ + pr * 2;
  unsigned qp = *(const unsigned*)&qkv[base];
  unsigned kp = *(const unsigned*)&qkv[base + D_];
  unsigned vp = *(const unsigned*)&qkv[base + 2 * D_];
  float qe = b2f((unsigned short)qp), qo = b2f((unsigned short)(qp >> 16));
  float ke = b2f((unsigned short)kp), ko = b2f((unsigned short)(kp >> 16));
  float c = cs[s * 32 + pr], sv = sn[s * 32 + pr];
  size_t ob = ((size_t)(b * H_ + h)) * (S_ * HD_) + (size_t)s * HD_ + pr * 2;
  unsigned qw = (unsigned)f2b(qe * c - qo * sv) | ((unsigned)f2b(qe * sv + qo * c) << 16);
  unsigned kw = (unsigned)f2b(ke * c - ko * sv) | ((unsigned)f2b(ke * sv + ko * c) << 16);
  *(unsigned*)&q[ob] = qw;
  *(unsigned*)&k[ob] = kw;
  *(unsigned*)&v[ob] = vp;
}

// ------- v transpose per bh: [bh][S][HD] -> [bh][HD][S] -------
__global__ __launch_bounds__(256) void vtrans(const unsigned short* __restrict__ v,
                                              unsigned short* __restrict__ vT) {
  __shared__ unsigned short t[64][72];
  const int st = blockIdx.x, bh = blockIdx.y;
  const int row = threadIdx.x >> 2, c = (threadIdx.x & 3) * 16;
  const unsigned short* vb = v + (size_t)bh * (S_ * HD_);
  unsigned short* vo = vT + (size_t)bh * (HD_ * S_);
  *(uint4*)&t[row][c]     = *(const uint4*)&vb[(size_t)(st * 64 + row) * HD_ + c];
  *(uint4*)&t[row][c + 8] = *(const uint4*)&vb[(size_t)(st * 64 + row) * HD_ + c + 8];
  __syncthreads();
  unsigned short buf[16];
  #pragma unroll
  for (int j = 0; j < 16; j++) buf[j] = t[c + j][row];
  *(uint4*)&vo[(size_t)row * S_ + st * 64 + c]     = *(uint4*)&buf[0];
  *(uint4*)&vo[(size_t)row * S_ + st * 64 + c + 8] = *(uint4*)&buf[8];
}

// ------- MFMA flash attention: q,k [bh][S][64] bf16, vT [bh][64][S] bf16 -> out bf16 (B,S,D)
__global__ __launch_bounds__(256) void attn_mfma(const unsigned short* __restrict__ qg,
                                                 const unsigned short* __restrict__ kg,
                                                 const unsigned short* __restrict__ vTg,
                                                 unsigned short* __restrict__ o) {
  __shared__ unsigned short ks[64 * 72];  // [kcol][d]
  __shared__ unsigned short vs[64 * 72];  // [d][kcol]
  __shared__ unsigned short ps[64 * 72];  // [qrow][kcol]
  const int qt = (S_ / 64 - 1) - blockIdx.x;  // heavy tiles first
  const int bh = blockIdx.y;
  const int b = bh >> 4, h = bh & 15;
  const unsigned short* qb = qg + (size_t)bh * (S_ * HD_);
  const unsigned short* kb = kg + (size_t)bh * (S_ * HD_);
  const unsigned short* vb = vTg + (size_t)bh * (HD_ * S_);
  const int tid = threadIdx.x, lane = tid & 63, wave = tid >> 6;
  const int fr = lane & 15;
  const int kq8 = (lane >> 4) * 8;
  const int srow = tid >> 2;
  const int sc = (tid & 3) * 16;

  short8 qf[2];
  {
    const int qrow = qt * 64 + wave * 16 + fr;
    qf[0] = *(const short8*)&qb[(size_t)qrow * HD_ + kq8];
    qf[1] = *(const short8*)&qb[(size_t)qrow * HD_ + 32 + kq8];
  }
  floatx4 zv = {0.f, 0.f, 0.f, 0.f};
  float m_run[4], l_run[4];
  floatx4 oacc[4];
  #pragma unroll
  for (int r = 0; r < 4; r++) { m_run[r] = -1e30f; l_run[r] = 0.f; }
  #pragma unroll
  for (int di = 0; di < 4; di++) oacc[di] = zv;

  const int rbase = wave * 16 + (lane >> 4) * 4;  // q row base within tile (per lane)

  for (int kt = 0; kt <= qt; kt++) {
    if (kt) __syncthreads();
    {
      const unsigned short* kr = &kb[(size_t)(kt * 64 + srow) * HD_ + sc];
      *(uint4*)&ks[srow * 72 + sc]     = *(const uint4*)kr;
      *(uint4*)&ks[srow * 72 + sc + 8] = *(const uint4*)(kr + 8);
      const unsigned short* vr = &vb[(size_t)srow * S_ + kt * 64 + sc];
      *(uint4*)&vs[srow * 72 + sc]     = *(const uint4*)vr;
      *(uint4*)&vs[srow * 72 + sc + 8] = *(const uint4*)(vr + 8);
    }
    __syncthreads();
    floatx4 s4[4];
    #pragma unroll
    for (int ni = 0; ni < 4; ni++) {
      short8 kf0 = *(const short8*)&ks[(ni * 16 + fr) * 72 + kq8];
      short8 kf1 = *(const short8*)&ks[(ni * 16 + fr) * 72 + 32 + kq8];
      floatx4 a = __builtin_amdgcn_mfma_f32_16x16x32_bf16(qf[0], kf0, zv, 0, 0, 0);
      s4[ni] = __builtin_amdgcn_mfma_f32_16x16x32_bf16(qf[1], kf1, a, 0, 0, 0);
    }
    const bool diag = (kt == qt);
    #pragma unroll
    for (int r = 0; r < 4; r++) {
      float sr[4];
      #pragma unroll
      for (int ni = 0; ni < 4; ni++) {
        float sv = s4[ni][r] * 0.125f;
        if (diag && (ni * 16 + fr > rbase + r)) sv = -1e9f;
        sr[ni] = sv;
      }
      float mx = fmaxf(fmaxf(sr[0], sr[1]), fmaxf(sr[2], sr[3]));
      #pragma unroll
      for (int off = 1; off < 16; off <<= 1) mx = fmaxf(mx, __shfl_xor(mx, off, 64));
      float mn = fmaxf(m_run[r], mx);
      float alpha = __expf(m_run[r] - mn);
      float rs = 0.f;
      #pragma unroll
      for (int ni = 0; ni < 4; ni++) {
        float pv = __expf(sr[ni] - mn);
        rs += pv;
        ps[(rbase + r) * 72 + ni * 16 + fr] = f2b(pv);
      }
      #pragma unroll
      for (int off = 1; off < 16; off <<= 1) rs += __shfl_xor(rs, off, 64);
      l_run[r] = l_run[r] * alpha + rs;
      m_run[r] = mn;
      #pragma unroll
      for (int di = 0; di < 4; di++) oacc[di][r] *= alpha;
    }
    #pragma unroll
    for (int kp = 0; kp < 2; kp++) {
      short8 pa = *(const short8*)&ps[(wave * 16 + fr) * 72 + kp * 32 + kq8];
      #pragma unroll
      for (int di = 0; di < 4; di++) {
        short8 vf = *(const short8*)&vs[(di * 16 + fr) * 72 + kp * 32 + kq8];
        oacc[di] = __builtin_amdgcn_mfma_f32_16x16x32_bf16(pa, vf, oacc[di], 0, 0, 0);
      }
    }
  }
  float inv[4];
  #pragma unroll
  for (int r = 0; r < 4; r++) inv[r] = 1.f / l_run[r];
  #pragma unroll
  for (int di = 0; di < 4; di++) {
    #pragma unroll
    for (int r = 0; r < 4; r++) {
      int srow_g = qt * 64 + rbase + r;
      o[((size_t)(b * S_ + srow_g)) * D_ + h * HD_ + di * 16 + fr] = f2b(oacc[di][r] * inv[r]);
    }
  }
}

// ------- bias concat for fused gate/up GEMM -------
__global__ __launch_bounds__(256) void concat_bias(const float* __restrict__ bg_,
                                                   const float* __restrict__ bu_,
                                                   float* __restrict__ bgu) {
  int n = blockIdx.x * 256 + threadIdx.x;  // 0..2*MPAD-1
  float v = 0.f;
  if (n < MPAD) { if (n < MFF) v = bg_[n]; }
  else { int m = n - MPAD; if (m < MFF) v = bu_[m]; }
  bgu[n] = v;
}

// ------- swiglu: act[row][n] = silu(g)*u from fused gu buffer -------
__global__ __launch_bounds__(256) void swiglu_kernel(const unsigned short* __restrict__ gu,
                                                     unsigned short* __restrict__ act) {
  int n = blockIdx.x * 256 + threadIdx.x;
  int row = blockIdx.y;
  float a = 0.f;
  if (n < MFF) {
    float gv = b2f(gu[(size_t)row * (2 * MPAD) + n]);
    float uv = b2f(gu[(size_t)row * (2 * MPAD) + MPAD + n]);
    a = gv / (1.f + __expf(-gv)) * uv;
  }
  act[(size_t)row * MPAD + n] = f2b(a);
}

// ------- head GEMV: 500 blocks x 64 cols, 16-way k-split, float4 W loads -------
__global__ __launch_bounds__(256) void head_kernel(const float* __restrict__ hf,
                                                   const float* __restrict__ Wh,
                                                   const float* __restrict__ bh_,
                                                   float* __restrict__ out) {
  __shared__ float hs[2 * D_];
  __shared__ float r0[256][4], r1[256][4];
  const int t = threadIdx.x;
  {
    float4* hs4 = (float4*)hs;
    const float4* hf4 = (const float4*)hf;
    hs4[t] = hf4[t];
    hs4[t + 256] = hf4[t + 256];
  }
  __syncthreads();
  const int cg  = t & 15;   // float4 column group within the 64-col block
  const int ksl = t >> 4;   // 16-way k split, 64 k each
  const int col = blockIdx.x * 64 + cg * 4;
  const float* wp  = Wh + (size_t)(ksl * 64) * V_ + col;
  const float* h0p = &hs[ksl * 64];
  const float* h1p = &hs[D_ + ksl * 64];
  float a0x = 0.f, a0y = 0.f, a0z = 0.f, a0w = 0.f;
  float a1x = 0.f, a1y = 0.f, a1z = 0.f, a1w = 0.f;
  #pragma unroll 8
  for (int k = 0; k < 64; k++) {
    float4 w = *(const float4*)(wp + (size_t)k * V_);
    float h0 = h0p[k], h1 = h1p[k];
    a0x = fmaf(h0, w.x, a0x); a0y = fmaf(h0, w.y, a0y);
    a0z = fmaf(h0, w.z, a0z); a0w = fmaf(h0, w.w, a0w);
    a1x = fmaf(h1, w.x, a1x); a1y = fmaf(h1, w.y, a1y);
    a1z = fmaf(h1, w.z, a1z); a1w = fmaf(h1, w.w, a1w);
  }
  r0[t][0] = a0x; r0[t][1] = a0y; r0[t][2] = a0z; r0[t][3] = a0w;
  r1[t][0] = a1x; r1[t][1] = a1y; r1[t][2] = a1z; r1[t][3] = a1w;
  __syncthreads();
  if (t < 16) {
    float s0[4] = {0.f, 0.f, 0.f, 0.f}, s1[4] = {0.f, 0.f, 0.f, 0.f};
    #pragma unroll
    for (int s = 0; s < 16; s++) {
      #pragma unroll
      for (int j = 0; j < 4; j++) {
        s0[j] += r0[s * 16 + t][j];
        s1[j] += r1[s * 16 + t][j];
      }
    }
    int c = blockIdx.x * 64 + t * 4;
    float4 bv = *(const float4*)&bh_[c];
    float4 o0 = {s0[0] + bv.x, s0[1] + bv.y, s0[2] + bv.z, s0[3] + bv.w};
    float4 o1 = {s1[0] + bv.x, s1[1] + bv.y, s1[2] + bv.z, s1[3] + bv.w};
    *(float4*)&out[c]      = o0;
    *(float4*)&out[V_ + c] = o1;
  }
}

// ======================= launcher =======================
extern "C" void kernel_launch(void* const* d_in, const int* in_sizes, int n_in,
                              void* d_out, int out_size, void* d_ws, size_t ws_size,
                              hipStream_t stream) {
  const int*   tokens = (const int*)d_in[0];
  const float* embed  = (const float*)d_in[1];
  const float* Wqkv   = (const float*)d_in[2];
  const float* bqkv   = (const float*)d_in[3];
  const float* Wout   = (const float*)d_in[4];
  const float* bout   = (const float*)d_in[5];
  const float* ln1    = (const float*)d_in[6];
  const float* ln2    = (const float*)d_in[7];
  const float* Wg     = (const float*)d_in[8];
  const float* bg     = (const float*)d_in[9];
  const float* Wu     = (const float*)d_in[10];
  const float* bu     = (const float*)d_in[11];
  const float* Wd     = (const float*)d_in[12];
  const float* bd     = (const float*)d_in[13];
  const float* lnf    = (const float*)d_in[14];
  const float* Whead  = (const float*)d_in[15];
  const float* bhead  = (const float*)d_in[16];
  float* out = (float*)d_out;

  char* base = (char*)d_ws;
  size_t off = 0;
  auto alloc = [&](size_t bytes) -> char* {
    char* r = base + off;
    off += (bytes + 255) & ~(size_t)255;
    return r;
  };
  const size_t NROW = (size_t)B_ * S_;  // 2048
  unsigned short* WqkvT = (unsigned short*)alloc((size_t)L_ * 3072 * 1024 * 2);
  unsigned short* WoutT = (unsigned short*)alloc((size_t)L_ * 1024 * 1024 * 2);
  unsigned short* WguT  = (unsigned short*)alloc((size_t)L_ * 2 * MPAD * 1024 * 2);
  unsigned short* WdT   = (unsigned short*)alloc((size_t)L_ * 1024 * MPAD * 2);
  float*          x     = (float*)alloc(NROW * D_ * 4);
  unsigned short* h     = (unsigned short*)alloc(NROW * D_ * 2);
  unsigned short* qkv   = (unsigned short*)alloc(NROW * 3072 * 2);  // act aliases
  unsigned short* qb    = (unsigned short*)alloc(NROW * HD_ * H_ * 2);
  unsigned short* kb    = (unsigned short*)alloc(NROW * HD_ * H_ * 2);
  unsigned short* vb    = (unsigned short*)alloc(NROW * HD_ * H_ * 2);  // aout aliases
  unsigned short* vT    = (unsigned short*)alloc(NROW * HD_ * H_ * 2);
  unsigned short* gu    = (unsigned short*)alloc(NROW * 2 * MPAD * 2);
  float*          bgu   = (float*)alloc(2 * MPAD * 4);
  float*          csT   = (float*)alloc((size_t)S_ * 32 * 4);
  float*          snT   = (float*)alloc((size_t)S_ * 32 * 4);
  float*          hfin  = (float*)alloc((size_t)B_ * D_ * 4);
  unsigned short* act   = qkv;  // dead after rope_apply; reused after attention
  unsigned short* aout  = vb;   // dead after vtrans; reused as attention output

  // ---- weight transposes (per call; ws is re-poisoned) ----
  for (int l = 0; l < L_; l++) {
    transpose_conv<<<dim3(3072 / 64, 1024 / 64), 256, 0, stream>>>(
        Wqkv + (size_t)l * 1024 * 3072, WqkvT + (size_t)l * 3072 * 1024, 1024, 3072, 1024, 3072);
    transpose_conv<<<dim3(1024 / 64, 1024 / 64), 256, 0, stream>>>(
        Wout + (size_t)l * 1024 * 1024, WoutT + (size_t)l * 1024 * 1024, 1024, 1024, 1024, 1024);
    transpose_conv<<<dim3(MPAD / 64, 1024 / 64), 256, 0, stream>>>(
        Wg + (size_t)l * 1024 * MFF, WguT + (size_t)l * 2 * MPAD * 1024, 1024, MFF, 1024, MPAD);
    transpose_conv<<<dim3(MPAD / 64, 1024 / 64), 256, 0, stream>>>(
        Wu + (size_t)l * 1024 * MFF, WguT + (size_t)l * 2 * MPAD * 1024 + (size_t)MPAD * 1024,
        1024, MFF, 1024, MPAD);
    transpose_conv<<<dim3(1024 / 64, MPAD / 64), 256, 0, stream>>>(
        Wd + (size_t)l * MFF * 1024, WdT + (size_t)l * 1024 * MPAD, MFF, 1024, MPAD, 1024);
  }
  rope_table<<<dim3(S_ * 32 / 256), 256, 0, stream>>>(csT, snT);
  embed_kernel<<<dim3(NROW), 256, 0, stream>>>(tokens, embed, x);

  for (int l = 0; l < L_; l++) {
    rmsnorm_bf<<<dim3(NROW), 256, 0, stream>>>(x, ln1 + (size_t)l * D_, h);
    gemm_bt<2, 128><<<dim3(3072 / 128, NROW / 128), 256, 0, stream>>>(
        h, WqkvT + (size_t)l * 3072 * 1024, bqkv + (size_t)l * 3072, nullptr, qkv,
        3072, 1024, 1024, 1024, 3072, 3072);
    rope_apply<<<dim3((B_ * S_ * H_ * 32) / 256), 256, 0, stream>>>(qkv, csT, snT, qb, kb, vb);
    vtrans<<<dim3(S_ / 64, B_ * H_), 256, 0, stream>>>(vb, vT);
    attn_mfma<<<dim3(S_ / 64, B_ * H_), 256, 0, stream>>>(qb, kb, vT, aout);
    gemm_bt<1, 64><<<dim3(1024 / 128, NROW / 64), 256, 0, stream>>>(
        aout, WoutT + (size_t)l * 1024 * 1024, bout + (size_t)l * D_, x, x,
        1024, 1024, 1024, 1024, 1024, 1024);
    rmsnorm_bf<<<dim3(NROW), 256, 0, stream>>>(x, ln2 + (size_t)l * D_, h);
    concat_bias<<<dim3(2 * MPAD / 256), 256, 0, stream>>>(
        bg + (size_t)l * MFF, bu + (size_t)l * MFF, bgu);
    gemm_bt<2, 128><<<dim3(2 * MPAD / 128, NROW / 128), 256, 0, stream>>>(
        h, WguT + (size_t)l * 2 * MPAD * 1024, bgu, nullptr, gu,
        2 * MPAD, 1024, 1024, 1024, 2 * MPAD, 2 * MPAD);
    swiglu_kernel<<<dim3(MPAD / 256, NROW), 256, 0, stream>>>(gu, act);
    gemm_bt<1, 64><<<dim3(1024 / 128, NROW / 64), 256, 0, stream>>>(
        act, WdT + (size_t)l * 1024 * MPAD, bd + (size_t)l * D_, x, x,
        1024, MPAD, MPAD, MPAD, 1024, 1024);
  }

  rmsnorm_final<<<dim3(B_), 256, 0, stream>>>(x, lnf, hfin);
  head_kernel<<<dim3(V_ / 64), 256, 0, stream>>>(hfin, Whead, bhead, out);
}

// Round 4
// 1183.094 us; speedup vs baseline: 1.0748x; 1.0748x over previous
//
#include <hip/hip_runtime.h>

#define B_   2
#define S_   1024
#define D_   1024
#define H_   16
#define HD_  64
#define L_   4
#define MFF  2730
#define MPAD 2816
#define V_   32000

typedef __attribute__((ext_vector_type(8))) short   short8;
typedef __attribute__((ext_vector_type(4))) float   floatx4;

__device__ __forceinline__ unsigned short f2b(float f) {
  unsigned u = __float_as_uint(f);
  u += 0x7fffu + ((u >> 16) & 1u);
  return (unsigned short)(u >> 16);
}
__device__ __forceinline__ float b2f(unsigned short s) {
  return __uint_as_float(((unsigned)s) << 16);
}

// async global->LDS, 16B per lane. LDS dst must be wave-uniform base; HW adds lane*16.
__device__ __forceinline__ void gload16(const unsigned short* g, unsigned short* l) {
  __builtin_amdgcn_global_load_lds(
      (const __attribute__((address_space(1))) unsigned int*)(unsigned long long)g,
      (__attribute__((address_space(3))) unsigned int*)(unsigned int)(unsigned long long)l,
      16, 0, 0);
}

// raw workgroup barrier with compiler memory fences (no vmcnt drain).
__device__ __forceinline__ void wgbar() {
  asm volatile("" ::: "memory");
  __builtin_amdgcn_s_barrier();
  asm volatile("" ::: "memory");
}

// ---------------- embed gather ----------------
__global__ __launch_bounds__(256) void embed_kernel(const int* __restrict__ tokens,
                                                    const float* __restrict__ embed,
                                                    float* __restrict__ x) {
  int row = blockIdx.x;
  int tok = tokens[row];
  int c = threadIdx.x * 4;
  float4 v = *(const float4*)&embed[(size_t)tok * D_ + c];
  *(float4*)&x[(size_t)row * D_ + c] = v;
}

// ---------------- rmsnorm (f32 in -> bf16 out) ----------------
__global__ __launch_bounds__(256) void rmsnorm_bf(const float* __restrict__ x,
                                                  const float* __restrict__ w,
                                                  unsigned short* __restrict__ out) {
  int row = blockIdx.x, t = threadIdx.x;
  float4 xv = *(const float4*)&x[(size_t)row * D_ + t * 4];
  float ss = xv.x * xv.x + xv.y * xv.y + xv.z * xv.z + xv.w * xv.w;
  #pragma unroll
  for (int off = 1; off < 64; off <<= 1) ss += __shfl_xor(ss, off, 64);
  __shared__ float sred[4];
  if ((t & 63) == 0) sred[t >> 6] = ss;
  __syncthreads();
  ss = sred[0] + sred[1] + sred[2] + sred[3];
  float rr = rsqrtf(ss * (1.f / (float)D_) + 1e-6f);
  float4 wv = *(const float4*)&w[t * 4];
  size_t o = (size_t)row * D_ + t * 4;
  out[o + 0] = f2b(xv.x * rr * wv.x);
  out[o + 1] = f2b(xv.y * rr * wv.y);
  out[o + 2] = f2b(xv.z * rr * wv.z);
  out[o + 3] = f2b(xv.w * rr * wv.w);
}

// ---------------- final rmsnorm (last token rows, f32 out) ----------------
__global__ __launch_bounds__(256) void rmsnorm_final(const float* __restrict__ x,
                                                     const float* __restrict__ w,
                                                     float* __restrict__ out) {
  int b = blockIdx.x, t = threadIdx.x;
  const float* xr = x + ((size_t)b * S_ + (S_ - 1)) * D_;
  float4 xv = *(const float4*)&xr[t * 4];
  float ss = xv.x * xv.x + xv.y * xv.y + xv.z * xv.z + xv.w * xv.w;
  #pragma unroll
  for (int off = 1; off < 64; off <<= 1) ss += __shfl_xor(ss, off, 64);
  __shared__ float sred[4];
  if ((t & 63) == 0) sred[t >> 6] = ss;
  __syncthreads();
  ss = sred[0] + sred[1] + sred[2] + sred[3];
  float rr = rsqrtf(ss * (1.f / (float)D_) + 1e-6f);
  float4 wv = *(const float4*)&w[t * 4];
  size_t o = (size_t)b * D_ + t * 4;
  out[o + 0] = xv.x * rr * wv.x;
  out[o + 1] = xv.y * rr * wv.y;
  out[o + 2] = xv.z * rr * wv.z;
  out[o + 3] = xv.w * rr * wv.w;
}

// -------- weight transpose + f32->bf16, 64x64 tiles (K x N -> Npad x Kpad) --------
__global__ __launch_bounds__(256) void transpose_conv(const float* __restrict__ W,
                                                      unsigned short* __restrict__ Wt,
                                                      int K, int N, int Kpad, int Npad) {
  __shared__ float tile[64][65];
  const int tx = threadIdx.x & 15, ty = threadIdx.x >> 4;
  const int k0 = blockIdx.y * 64, n0 = blockIdx.x * 64;
  #pragma unroll
  for (int i = 0; i < 4; i++) {
    int kk = k0 + ty + i * 16;
    int nn = n0 + tx * 4;
    float4 v = {0.f, 0.f, 0.f, 0.f};
    if (kk < K) {
      if (nn + 3 < N) v = *(const float4*)&W[(size_t)kk * N + nn];
      else {
        if (nn + 0 < N) v.x = W[(size_t)kk * N + nn + 0];
        if (nn + 1 < N) v.y = W[(size_t)kk * N + nn + 1];
        if (nn + 2 < N) v.z = W[(size_t)kk * N + nn + 2];
      }
    }
    tile[ty + i * 16][tx * 4 + 0] = v.x;
    tile[ty + i * 16][tx * 4 + 1] = v.y;
    tile[ty + i * 16][tx * 4 + 2] = v.z;
    tile[ty + i * 16][tx * 4 + 3] = v.w;
  }
  __syncthreads();
  #pragma unroll
  for (int i = 0; i < 4; i++) {
    int nn = n0 + ty + i * 16;
    int kk = k0 + tx * 4;
    if (nn < Npad && kk < Kpad) {
      ushort4 o;
      o.x = f2b(tile[tx * 4 + 0][ty + i * 16]);
      o.y = f2b(tile[tx * 4 + 1][ty + i * 16]);
      o.z = f2b(tile[tx * 4 + 2][ty + i * 16]);
      o.w = f2b(tile[tx * 4 + 3][ty + i * 16]);
      *(ushort4*)&Wt[(size_t)nn * Kpad + kk] = o;
    }
  }
}

// ---- bf16 MFMA GEMM, A[M][K], B^T[N][K], MTILE x 128 tile ----
// 3-buffer, 2-AHEAD circular pipeline with counted vmcnt (T3+T4 deepened):
// tile k+2's loads issue during phase k -> issue-to-use distance ~2 compute
// phases (~400cy) >= L2 latency, vs 1-deep's ~200cy which left a per-K-step
// stall. Steady-state wait: vmcnt(2*LOADS) -- two stages stay in flight
// across barriers. Slot reuse: stage into slot s at iter k+1 was last read
// at iter k; trailing barrier protects it.
// (R3 lesson: XCD swizzle reverted -- weights are L3-resident, swizzle cost 2%.)
// EPI: 0 = f32 out, 1 = f32 out + residual, 2 = bf16 out
template <int EPI, int MTILE>
__global__ __launch_bounds__(256) void gemm_bt(const unsigned short* __restrict__ A,
                                               const unsigned short* __restrict__ B,
                                               const float* __restrict__ bias,
                                               const float* __restrict__ res,
                                               void* __restrict__ Cout,
                                               int N, int K, int lda, int ldb, int ldc,
                                               int Nlog) {
  constexpr int MW = MTILE / 32;           // m-frags per wave
  constexpr int LOADS = MTILE / 64 + 2;    // gload16 per wave per stage
  __shared__ unsigned short As[3][MTILE * 32];
  __shared__ unsigned short Bs[3][128 * 32];
  const int tid = threadIdx.x;
  const int lane = tid & 63, wave = tid >> 6;
  const int m0 = blockIdx.y * MTILE, n0 = blockIdx.x * 128;
  const int rS = tid >> 2;
  const int kS = (tid & 3) * 8;
  const int fr = lane & 15;
  const int kq = (lane >> 4) * 8;
  const int wm = (wave & 1) * (MTILE / 2), wn = (wave >> 1) * 64;

  const unsigned short* Ab = A + (size_t)(m0 + rS) * lda + kS;
  const unsigned short* Bb = B + (size_t)(n0 + rS) * ldb + kS;

  floatx4 zv = {0.f, 0.f, 0.f, 0.f};
  floatx4 acc[MW][4];
  #pragma unroll
  for (int mi = 0; mi < MW; mi++)
    #pragma unroll
    for (int ni = 0; ni < 4; ni++) acc[mi][ni] = zv;

  auto stage = [&](int buf, int k0) {
    #pragma unroll
    for (int i = 0; i < MTILE / 64; i++)
      gload16(Ab + (size_t)(i * 64) * lda + k0, &As[buf][i * 2048 + wave * 512]);
    #pragma unroll
    for (int i = 0; i < 2; i++)
      gload16(Bb + (size_t)(i * 64) * ldb + k0, &Bs[buf][i * 2048 + wave * 512]);
  };

  const int nk = K / 32;  // K >= 64 always here
  stage(0, 0);
  stage(1, 32);
  int cur = 0, stg = 2;
  for (int kt = 0; kt < nk; kt++) {
    if (kt + 2 < nk) {
      stage(stg, (kt + 2) * 32);
      // steady state: stages kt+1, kt+2 outstanding -> wait only tile kt
      if constexpr (LOADS == 4)
        asm volatile("s_waitcnt vmcnt(8)" ::: "memory");
      else
        asm volatile("s_waitcnt vmcnt(6)" ::: "memory");
    } else if (kt + 1 < nk) {
      if constexpr (LOADS == 4)
        asm volatile("s_waitcnt vmcnt(4)" ::: "memory");
      else
        asm volatile("s_waitcnt vmcnt(3)" ::: "memory");
    } else {
      asm volatile("s_waitcnt vmcnt(0)" ::: "memory");
    }
    wgbar();  // current tile fully in LDS (each wave waited its own loads)
    short8 af[MW], bfv[4];
    #pragma unroll
    for (int mi = 0; mi < MW; mi++) af[mi] = *(const short8*)&As[cur][(wm + mi * 16 + fr) * 32 + kq];
    #pragma unroll
    for (int ni = 0; ni < 4; ni++) bfv[ni] = *(const short8*)&Bs[cur][(wn + ni * 16 + fr) * 32 + kq];
    #pragma unroll
    for (int mi = 0; mi < MW; mi++)
      #pragma unroll
      for (int ni = 0; ni < 4; ni++)
        acc[mi][ni] = __builtin_amdgcn_mfma_f32_16x16x32_bf16(af[mi], bfv[ni], acc[mi][ni], 0, 0, 0);
    wgbar();  // all waves done reading buf[cur]; safe to restage it next iter
    cur = (cur == 2) ? 0 : cur + 1;
    stg = (stg == 2) ? 0 : stg + 1;
  }

  const int cr = (lane >> 4) * 4;
  const int cc = lane & 15;
  #pragma unroll
  for (int mi = 0; mi < MW; mi++) {
    #pragma unroll
    for (int ni = 0; ni < 4; ni++) {
      int col = n0 + wn + ni * 16 + cc;
      float bv = (col < Nlog) ? bias[col] : 0.f;
      #pragma unroll
      for (int r = 0; r < 4; r++) {
        int row = m0 + wm + mi * 16 + cr + r;
        float val = acc[mi][ni][r] + bv;
        if constexpr (EPI == 1) val += res[(size_t)row * ldc + col];
        if constexpr (EPI == 2)
          ((unsigned short*)Cout)[(size_t)row * ldc + col] = f2b(val);
        else
          ((float*)Cout)[(size_t)row * ldc + col] = val;
      }
    }
  }
}

// ---------------- rope table (double precision) ----------------
__global__ __launch_bounds__(256) void rope_table(float* __restrict__ cs, float* __restrict__ sn) {
  int i = blockIdx.x * 256 + threadIdx.x;
  int s = i >> 5, f = i & 31;
  double inv = pow(10000.0, -(double)(2 * f) / 64.0);
  double ang = (double)s * inv;
  cs[i] = (float)cos(ang);
  sn[i] = (float)sin(ang);
}

// ------- rope apply (qkv bf16 -> q,k,v bf16 in (B*H,S,HD)) -------
__global__ __launch_bounds__(256) void rope_apply(const unsigned short* __restrict__ qkv,
                                                  const float* __restrict__ cs,
                                                  const float* __restrict__ sn,
                                                  unsigned short* __restrict__ q,
                                                  unsigned short* __restrict__ k,
                                                  unsigned short* __restrict__ v) {
  int i = blockIdx.x * 256 + threadIdx.x;  // B*S*H*32
  int pr = i & 31;
  int h  = (i >> 5) & 15;
  int s  = (i >> 9) & 1023;
  int b  = i >> 19;
  size_t base = ((size_t)(b * S_ + s)) * (3 * D_) + h * HD_ + pr * 2;
  unsigned qp = *(const unsigned*)&qkv[base];
  unsigned kp = *(const unsigned*)&qkv[base + D_];
  unsigned vp = *(const unsigned*)&qkv[base + 2 * D_];
  float qe = b2f((unsigned short)qp), qo = b2f((unsigned short)(qp >> 16));
  float ke = b2f((unsigned short)kp), ko = b2f((unsigned short)(kp >> 16));
  float c = cs[s * 32 + pr], sv = sn[s * 32 + pr];
  size_t ob = ((size_t)(b * H_ + h)) * (S_ * HD_) + (size_t)s * HD_ + pr * 2;
  unsigned qw = (unsigned)f2b(qe * c - qo * sv) | ((unsigned)f2b(qe * sv + qo * c) << 16);
  unsigned kw = (unsigned)f2b(ke * c - ko * sv) | ((unsigned)f2b(ke * sv + ko * c) << 16);
  *(unsigned*)&q[ob] = qw;
  *(unsigned*)&k[ob] = kw;
  *(unsigned*)&v[ob] = vp;
}

// ------- v transpose per bh: [bh][S][HD] -> [bh][HD][S] -------
__global__ __launch_bounds__(256) void vtrans(const unsigned short* __restrict__ v,
                                              unsigned short* __restrict__ vT) {
  __shared__ unsigned short t[64][72];
  const int st = blockIdx.x, bh = blockIdx.y;
  const int row = threadIdx.x >> 2, c = (threadIdx.x & 3) * 16;
  const unsigned short* vb = v + (size_t)bh * (S_ * HD_);
  unsigned short* vo = vT + (size_t)bh * (HD_ * S_);
  *(uint4*)&t[row][c]     = *(const uint4*)&vb[(size_t)(st * 64 + row) * HD_ + c];
  *(uint4*)&t[row][c + 8] = *(const uint4*)&vb[(size_t)(st * 64 + row) * HD_ + c + 8];
  __syncthreads();
  unsigned short buf[16];
  #pragma unroll
  for (int j = 0; j < 16; j++) buf[j] = t[c + j][row];
  *(uint4*)&vo[(size_t)row * S_ + st * 64 + c]     = *(uint4*)&buf[0];
  *(uint4*)&vo[(size_t)row * S_ + st * 64 + c + 8] = *(uint4*)&buf[8];
}

// ------- MFMA flash attention: q,k [bh][S][64] bf16, vT [bh][64][S] bf16 -> out bf16 (B,S,D)
__global__ __launch_bounds__(256) void attn_mfma(const unsigned short* __restrict__ qg,
                                                 const unsigned short* __restrict__ kg,
                                                 const unsigned short* __restrict__ vTg,
                                                 unsigned short* __restrict__ o) {
  __shared__ unsigned short ks[64 * 72];  // [kcol][d]
  __shared__ unsigned short vs[64 * 72];  // [d][kcol]
  __shared__ unsigned short ps[64 * 72];  // [qrow][kcol]
  const int qt = (S_ / 64 - 1) - blockIdx.x;  // heavy tiles first
  const int bh = blockIdx.y;
  const int b = bh >> 4, h = bh & 15;
  const unsigned short* qb = qg + (size_t)bh * (S_ * HD_);
  const unsigned short* kb = kg + (size_t)bh * (S_ * HD_);
  const unsigned short* vb = vTg + (size_t)bh * (HD_ * S_);
  const int tid = threadIdx.x, lane = tid & 63, wave = tid >> 6;
  const int fr = lane & 15;
  const int kq8 = (lane >> 4) * 8;
  const int srow = tid >> 2;
  const int sc = (tid & 3) * 16;

  short8 qf[2];
  {
    const int qrow = qt * 64 + wave * 16 + fr;
    qf[0] = *(const short8*)&qb[(size_t)qrow * HD_ + kq8];
    qf[1] = *(const short8*)&qb[(size_t)qrow * HD_ + 32 + kq8];
  }
  floatx4 zv = {0.f, 0.f, 0.f, 0.f};
  float m_run[4], l_run[4];
  floatx4 oacc[4];
  #pragma unroll
  for (int r = 0; r < 4; r++) { m_run[r] = -1e30f; l_run[r] = 0.f; }
  #pragma unroll
  for (int di = 0; di < 4; di++) oacc[di] = zv;

  const int rbase = wave * 16 + (lane >> 4) * 4;  // q row base within tile (per lane)

  for (int kt = 0; kt <= qt; kt++) {
    if (kt) __syncthreads();
    {
      const unsigned short* kr = &kb[(size_t)(kt * 64 + srow) * HD_ + sc];
      *(uint4*)&ks[srow * 72 + sc]     = *(const uint4*)kr;
      *(uint4*)&ks[srow * 72 + sc + 8] = *(const uint4*)(kr + 8);
      const unsigned short* vr = &vb[(size_t)srow * S_ + kt * 64 + sc];
      *(uint4*)&vs[srow * 72 + sc]     = *(const uint4*)vr;
      *(uint4*)&vs[srow * 72 + sc + 8] = *(const uint4*)(vr + 8);
    }
    __syncthreads();
    floatx4 s4[4];
    #pragma unroll
    for (int ni = 0; ni < 4; ni++) {
      short8 kf0 = *(const short8*)&ks[(ni * 16 + fr) * 72 + kq8];
      short8 kf1 = *(const short8*)&ks[(ni * 16 + fr) * 72 + 32 + kq8];
      floatx4 a = __builtin_amdgcn_mfma_f32_16x16x32_bf16(qf[0], kf0, zv, 0, 0, 0);
      s4[ni] = __builtin_amdgcn_mfma_f32_16x16x32_bf16(qf[1], kf1, a, 0, 0, 0);
    }
    const bool diag = (kt == qt);
    #pragma unroll
    for (int r = 0; r < 4; r++) {
      float sr[4];
      #pragma unroll
      for (int ni = 0; ni < 4; ni++) {
        float sv = s4[ni][r] * 0.125f;
        if (diag && (ni * 16 + fr > rbase + r)) sv = -1e9f;
        sr[ni] = sv;
      }
      float mx = fmaxf(fmaxf(sr[0], sr[1]), fmaxf(sr[2], sr[3]));
      #pragma unroll
      for (int off = 1; off < 16; off <<= 1) mx = fmaxf(mx, __shfl_xor(mx, off, 64));
      float mn = fmaxf(m_run[r], mx);
      float alpha = __expf(m_run[r] - mn);
      float rs = 0.f;
      #pragma unroll
      for (int ni = 0; ni < 4; ni++) {
        float pv = __expf(sr[ni] - mn);
        rs += pv;
        ps[(rbase + r) * 72 + ni * 16 + fr] = f2b(pv);
      }
      #pragma unroll
      for (int off = 1; off < 16; off <<= 1) rs += __shfl_xor(rs, off, 64);
      l_run[r] = l_run[r] * alpha + rs;
      m_run[r] = mn;
      #pragma unroll
      for (int di = 0; di < 4; di++) oacc[di][r] *= alpha;
    }
    #pragma unroll
    for (int kp = 0; kp < 2; kp++) {
      short8 pa = *(const short8*)&ps[(wave * 16 + fr) * 72 + kp * 32 + kq8];
      #pragma unroll
      for (int di = 0; di < 4; di++) {
        short8 vf = *(const short8*)&vs[(di * 16 + fr) * 72 + kp * 32 + kq8];
        oacc[di] = __builtin_amdgcn_mfma_f32_16x16x32_bf16(pa, vf, oacc[di], 0, 0, 0);
      }
    }
  }
  float inv[4];
  #pragma unroll
  for (int r = 0; r < 4; r++) inv[r] = 1.f / l_run[r];
  #pragma unroll
  for (int di = 0; di < 4; di++) {
    #pragma unroll
    for (int r = 0; r < 4; r++) {
      int srow_g = qt * 64 + rbase + r;
      o[((size_t)(b * S_ + srow_g)) * D_ + h * HD_ + di * 16 + fr] = f2b(oacc[di][r] * inv[r]);
    }
  }
}

// ------- bias concat for fused gate/up GEMM -------
__global__ __launch_bounds__(256) void concat_bias(const float* __restrict__ bg_,
                                                   const float* __restrict__ bu_,
                                                   float* __restrict__ bgu) {
  int n = blockIdx.x * 256 + threadIdx.x;  // 0..2*MPAD-1
  float v = 0.f;
  if (n < MPAD) { if (n < MFF) v = bg_[n]; }
  else { int m = n - MPAD; if (m < MFF) v = bu_[m]; }
  bgu[n] = v;
}

// ------- swiglu: act[row][n] = silu(g)*u from fused gu buffer -------
__global__ __launch_bounds__(256) void swiglu_kernel(const unsigned short* __restrict__ gu,
                                                     unsigned short* __restrict__ act) {
  int n = blockIdx.x * 256 + threadIdx.x;
  int row = blockIdx.y;
  float a = 0.f;
  if (n < MFF) {
    float gv = b2f(gu[(size_t)row * (2 * MPAD) + n]);
    float uv = b2f(gu[(size_t)row * (2 * MPAD) + MPAD + n]);
    a = gv / (1.f + __expf(-gv)) * uv;
  }
  act[(size_t)row * MPAD + n] = f2b(a);
}

// ------- head GEMV: 500 blocks x 64 cols, 16-way k-split, float4 W loads -------
__global__ __launch_bounds__(256) void head_kernel(const float* __restrict__ hf,
                                                   const float* __restrict__ Wh,
                                                   const float* __restrict__ bh_,
                                                   float* __restrict__ out) {
  __shared__ float hs[2 * D_];
  __shared__ float r0[256][4], r1[256][4];
  const int t = threadIdx.x;
  {
    float4* hs4 = (float4*)hs;
    const float4* hf4 = (const float4*)hf;
    hs4[t] = hf4[t];
    hs4[t + 256] = hf4[t + 256];
  }
  __syncthreads();
  const int cg  = t & 15;   // float4 column group within the 64-col block
  const int ksl = t >> 4;   // 16-way k split, 64 k each
  const int col = blockIdx.x * 64 + cg * 4;
  const float* wp  = Wh + (size_t)(ksl * 64) * V_ + col;
  const float* h0p = &hs[ksl * 64];
  const float* h1p = &hs[D_ + ksl * 64];
  float a0x = 0.f, a0y = 0.f, a0z = 0.f, a0w = 0.f;
  float a1x = 0.f, a1y = 0.f, a1z = 0.f, a1w = 0.f;
  #pragma unroll 8
  for (int k = 0; k < 64; k++) {
    float4 w = *(const float4*)(wp + (size_t)k * V_);
    float h0 = h0p[k], h1 = h1p[k];
    a0x = fmaf(h0, w.x, a0x); a0y = fmaf(h0, w.y, a0y);
    a0z = fmaf(h0, w.z, a0z); a0w = fmaf(h0, w.w, a0w);
    a1x = fmaf(h1, w.x, a1x); a1y = fmaf(h1, w.y, a1y);
    a1z = fmaf(h1, w.z, a1z); a1w = fmaf(h1, w.w, a1w);
  }
  r0[t][0] = a0x; r0[t][1] = a0y; r0[t][2] = a0z; r0[t][3] = a0w;
  r1[t][0] = a1x; r1[t][1] = a1y; r1[t][2] = a1z; r1[t][3] = a1w;
  __syncthreads();
  if (t < 16) {
    float s0[4] = {0.f, 0.f, 0.f, 0.f}, s1[4] = {0.f, 0.f, 0.f, 0.f};
    #pragma unroll
    for (int s = 0; s < 16; s++) {
      #pragma unroll
      for (int j = 0; j < 4; j++) {
        s0[j] += r0[s * 16 + t][j];
        s1[j] += r1[s * 16 + t][j];
      }
    }
    int c = blockIdx.x * 64 + t * 4;
    float4 bv = *(const float4*)&bh_[c];
    float4 o0 = {s0[0] + bv.x, s0[1] + bv.y, s0[2] + bv.z, s0[3] + bv.w};
    float4 o1 = {s1[0] + bv.x, s1[1] + bv.y, s1[2] + bv.z, s1[3] + bv.w};
    *(float4*)&out[c]      = o0;
    *(float4*)&out[V_ + c] = o1;
  }
}

// ======================= launcher =======================
extern "C" void kernel_launch(void* const* d_in, const int* in_sizes, int n_in,
                              void* d_out, int out_size, void* d_ws, size_t ws_size,
                              hipStream_t stream) {
  const int*   tokens = (const int*)d_in[0];
  const float* embed  = (const float*)d_in[1];
  const float* Wqkv   = (const float*)d_in[2];
  const float* bqkv   = (const float*)d_in[3];
  const float* Wout   = (const float*)d_in[4];
  const float* bout   = (const float*)d_in[5];
  const float* ln1    = (const float*)d_in[6];
  const float* ln2    = (const float*)d_in[7];
  const float* Wg     = (const float*)d_in[8];
  const float* bg     = (const float*)d_in[9];
  const float* Wu     = (const float*)d_in[10];
  const float* bu     = (const float*)d_in[11];
  const float* Wd     = (const float*)d_in[12];
  const float* bd     = (const float*)d_in[13];
  const float* lnf    = (const float*)d_in[14];
  const float* Whead  = (const float*)d_in[15];
  const float* bhead  = (const float*)d_in[16];
  float* out = (float*)d_out;

  char* base = (char*)d_ws;
  size_t off = 0;
  auto alloc = [&](size_t bytes) -> char* {
    char* r = base + off;
    off += (bytes + 255) & ~(size_t)255;
    return r;
  };
  const size_t NROW = (size_t)B_ * S_;  // 2048
  unsigned short* WqkvT = (unsigned short*)alloc((size_t)L_ * 3072 * 1024 * 2);
  unsigned short* WoutT = (unsigned short*)alloc((size_t)L_ * 1024 * 1024 * 2);
  unsigned short* WguT  = (unsigned short*)alloc((size_t)L_ * 2 * MPAD * 1024 * 2);
  unsigned short* WdT   = (unsigned short*)alloc((size_t)L_ * 1024 * MPAD * 2);
  float*          x     = (float*)alloc(NROW * D_ * 4);
  unsigned short* h     = (unsigned short*)alloc(NROW * D_ * 2);
  unsigned short* qkv   = (unsigned short*)alloc(NROW * 3072 * 2);  // act aliases
  unsigned short* qb    = (unsigned short*)alloc(NROW * HD_ * H_ * 2);
  unsigned short* kb    = (unsigned short*)alloc(NROW * HD_ * H_ * 2);
  unsigned short* vb    = (unsigned short*)alloc(NROW * HD_ * H_ * 2);  // aout aliases
  unsigned short* vT    = (unsigned short*)alloc(NROW * HD_ * H_ * 2);
  unsigned short* gu    = (unsigned short*)alloc(NROW * 2 * MPAD * 2);
  float*          bgu   = (float*)alloc(2 * MPAD * 4);
  float*          csT   = (float*)alloc((size_t)S_ * 32 * 4);
  float*          snT   = (float*)alloc((size_t)S_ * 32 * 4);
  float*          hfin  = (float*)alloc((size_t)B_ * D_ * 4);
  unsigned short* act   = qkv;  // dead after rope_apply; reused after attention
  unsigned short* aout  = vb;   // dead after vtrans; reused as attention output

  // ---- weight transposes (per call; ws is re-poisoned) ----
  for (int l = 0; l < L_; l++) {
    transpose_conv<<<dim3(3072 / 64, 1024 / 64), 256, 0, stream>>>(
        Wqkv + (size_t)l * 1024 * 3072, WqkvT + (size_t)l * 3072 * 1024, 1024, 3072, 1024, 3072);
    transpose_conv<<<dim3(1024 / 64, 1024 / 64), 256, 0, stream>>>(
        Wout + (size_t)l * 1024 * 1024, WoutT + (size_t)l * 1024 * 1024, 1024, 1024, 1024, 1024);
    transpose_conv<<<dim3(MPAD / 64, 1024 / 64), 256, 0, stream>>>(
        Wg + (size_t)l * 1024 * MFF, WguT + (size_t)l * 2 * MPAD * 1024, 1024, MFF, 1024, MPAD);
    transpose_conv<<<dim3(MPAD / 64, 1024 / 64), 256, 0, stream>>>(
        Wu + (size_t)l * 1024 * MFF, WguT + (size_t)l * 2 * MPAD * 1024 + (size_t)MPAD * 1024,
        1024, MFF, 1024, MPAD);
    transpose_conv<<<dim3(1024 / 64, MPAD / 64), 256, 0, stream>>>(
        Wd + (size_t)l * MFF * 1024, WdT + (size_t)l * 1024 * MPAD, MFF, 1024, MPAD, 1024);
  }
  rope_table<<<dim3(S_ * 32 / 256), 256, 0, stream>>>(csT, snT);
  embed_kernel<<<dim3(NROW), 256, 0, stream>>>(tokens, embed, x);

  for (int l = 0; l < L_; l++) {
    rmsnorm_bf<<<dim3(NROW), 256, 0, stream>>>(x, ln1 + (size_t)l * D_, h);
    gemm_bt<2, 128><<<dim3(3072 / 128, NROW / 128), 256, 0, stream>>>(
        h, WqkvT + (size_t)l * 3072 * 1024, bqkv + (size_t)l * 3072, nullptr, qkv,
        3072, 1024, 1024, 1024, 3072, 3072);
    rope_apply<<<dim3((B_ * S_ * H_ * 32) / 256), 256, 0, stream>>>(qkv, csT, snT, qb, kb, vb);
    vtrans<<<dim3(S_ / 64, B_ * H_), 256, 0, stream>>>(vb, vT);
    attn_mfma<<<dim3(S_ / 64, B_ * H_), 256, 0, stream>>>(qb, kb, vT, aout);
    gemm_bt<1, 64><<<dim3(1024 / 128, NROW / 64), 256, 0, stream>>>(
        aout, WoutT + (size_t)l * 1024 * 1024, bout + (size_t)l * D_, x, x,
        1024, 1024, 1024, 1024, 1024, 1024);
    rmsnorm_bf<<<dim3(NROW), 256, 0, stream>>>(x, ln2 + (size_t)l * D_, h);
    concat_bias<<<dim3(2 * MPAD / 256), 256, 0, stream>>>(
        bg + (size_t)l * MFF, bu + (size_t)l * MFF, bgu);
    gemm_bt<2, 128><<<dim3(2 * MPAD / 128, NROW / 128), 256, 0, stream>>>(
        h, WguT + (size_t)l * 2 * MPAD * 1024, bgu, nullptr, gu,
        2 * MPAD, 1024, 1024, 1024, 2 * MPAD, 2 * MPAD);
    swiglu_kernel<<<dim3(MPAD / 256, NROW), 256, 0, stream>>>(gu, act);
    gemm_bt<1, 64><<<dim3(1024 / 128, NROW / 64), 256, 0, stream>>>(
        act, WdT + (size_t)l * 1024 * MPAD, bd + (size_t)l * D_, x, x,
        1024, MPAD, MPAD, MPAD, 1024, 1024);
  }

  rmsnorm_final<<<dim3(B_), 256, 0, stream>>>(x, lnf, hfin);
  head_kernel<<<dim3(V_ / 64), 256, 0, stream>>>(hfin, Whead, bhead, out);
}